// Round 2
// baseline (384581.860 us; speedup 1.0000x reference)
//
#include <hip/hip_runtime.h>
#include <cmath>

#define TDEC 250
#define NB 256
#define EPS_A 1e-6f

// ---------------- ws float offsets ----------------
#define OFF_BAR    0
#define OFF_CTX    64                       // ctx_T   [768][64]
#define OFF_HATT   (OFF_CTX   + 49152)      // h_att_T [256][64]
#define OFF_H1     (OFF_HATT  + 16384)      // h1_T    [256][64]
#define OFF_H2     (OFF_H1    + 16384)      // h2_T    [256][64]
#define OFF_FRAME  (OFF_H2    + 16384)      // frame_T [400][64]
#define OFF_ALPHA  (OFF_FRAME + 25600)      // alpha   [64][512]
#define OFF_X      (OFF_ALPHA + 32768)      // x_T     [256][64]
#define OFF_X2     (OFF_X     + 16384)
#define OFF_X3     (OFF_X2    + 16384)
#define OFF_GICTX  (OFF_X3    + 16384)      // gi_ctx_T [768][64]
#define OFF_GHATT  (OFF_GICTX + 49152)      // gh_att_T [768][64]
#define OFF_GH1    (OFF_GHATT + 49152)
#define OFF_GH2    (OFF_GH1   + 49152)
#define OFF_H1S    (OFF_GH2   + 49152)      // h1s_T [256][64]
#define OFF_PRE    (OFF_H1S   + 16384)      // pre_T [128][64]
#define OFF_T1     (OFF_PRE   + 8192)       // t1_T  [128][64]
#define OFF_GT     (OFF_T1    + 8192)       // G_T   [168][64]
#define OFF_F8     (OFF_GT    + 10752)      // f8    [64][512][8]
#define OFF_LOGP   (OFF_F8    + 262144)     // [64][512]
#define OFF_E      (OFF_LOGP  + 32768)      // [64][512]

struct Prior { float v[11]; };

struct KArgs {
  const float *enc;
  const float *p1w,*p1b,*p2w,*p2b;
  const float *awi,*abi,*awh,*abh;
  const float *dWw,*dWb,*dVw,*dFw,*dUw,*dTw,*dTb,*dvw;
  const float *lw,*lb;
  const float *g1wi,*g1bi,*g1wh,*g1bh;
  const float *g2wi,*g2bi,*g2wh,*g2bh;
  const float *prw,*prb;
  float* ws; float* dout;
  Prior pr;
};

// ---------------- init: zero states + alpha onehot + barrier vars ----------------
__global__ __launch_bounds__(256) void k_init(float* ws) {
  int idx = blockIdx.x * 256 + threadIdx.x;
  int total = OFF_ALPHA + 32768;
  for (int i = idx; i < total; i += gridDim.x * 256) {
    float v = 0.f;
    if (i >= OFF_ALPHA && (((i - OFF_ALPHA) & 511) == 0)) v = 1.f;
    ws[i] = v;
  }
}

// ---------------- grid barrier (sense via generation counter) ----------------
__device__ __forceinline__ void gridbar(float* ws, unsigned* sgen) {
  __syncthreads();
  if (threadIdx.x == 0) {
    unsigned* cnt = (unsigned*)ws;
    unsigned* gen = (unsigned*)ws + 32;
    unsigned g = ++(*sgen);
    __threadfence();
    unsigned prev = __hip_atomic_fetch_add(cnt, 1u, __ATOMIC_ACQ_REL, __HIP_MEMORY_SCOPE_AGENT);
    if (prev == NB - 1u) {
      __hip_atomic_store(cnt, 0u, __ATOMIC_RELAXED, __HIP_MEMORY_SCOPE_AGENT);
      __hip_atomic_store(gen, g, __ATOMIC_RELEASE, __HIP_MEMORY_SCOPE_AGENT);
    } else {
      while (__hip_atomic_load(gen, __ATOMIC_ACQUIRE, __HIP_MEMORY_SCOPE_AGENT) < g)
        __builtin_amdgcn_s_sleep(1);
    }
  }
  __syncthreads();
}

// ---------------- generic tiled GEMM: outT[N][64] = W[N][ws] x actT[K][64] ----------------
struct GemmCfg {
  const float* A0; const float* A1; int K0; int K;
  const float* W; int wstr; int wofs;
  const float* bias; float* outT;
  int N, J, jgN, LR, activ;      // activ 0 none, 1 relu, 2 tanh
  int store;                     // 1: also scatter to dout (proj)
  float* dout; int tq;
};

__device__ __forceinline__ void gstore(const GemmCfg& c, int jj, int b, float v) {
  if (c.activ == 1) v = fmaxf(v, 0.f);
  else if (c.activ == 2) v = tanhf(v);
  c.outT[jj * 64 + b] = v;
  if (c.store == 1)
    c.dout[(size_t)b * 100000 + (jj / 5) * 1250 + c.tq * 5 + (jj % 5)] = v;
}

__device__ void gemm_run(const GemmCfg& c, int rb, float* sm) {
  int R = 1 << c.LR;
  int jg = rb % c.jgN, rg = rb / c.jgN;
  int r0 = rg * R, j0 = jg * c.J;
  int Kp = c.K + 4;
  for (int idx = threadIdx.x; idx < (c.K << c.LR); idx += 256) {
    int k = idx >> c.LR, r = idx & (R - 1);
    float v = (k < c.K0) ? c.A0[k * 64 + r0 + r] : c.A1[(k - c.K0) * 64 + r0 + r];
    sm[r * Kp + k] = v;
  }
  __syncthreads();
  int k4n = c.K >> 2;
  if ((c.J & 1) == 0) {
    int Jh = c.J >> 1;
    int np = Jh << c.LR;
    for (int e = threadIdx.x; e < np; e += 256) {
      int r = e & (R - 1); int q = e >> c.LR;
      int ja = j0 + q, jb = ja + Jh;
      const float4* wa = (const float4*)(c.W + (size_t)ja * c.wstr + c.wofs);
      const float4* wb = (const float4*)(c.W + (size_t)jb * c.wstr + c.wofs);
      const float4* ar = (const float4*)(sm + r * Kp);
      float acca = c.bias ? c.bias[ja] : 0.f;
      float accb = c.bias ? c.bias[jb] : 0.f;
      for (int k4 = 0; k4 < k4n; ++k4) {
        float4 a = ar[k4];
        float4 x = wa[k4], y = wb[k4];
        acca = fmaf(a.x,x.x, fmaf(a.y,x.y, fmaf(a.z,x.z, fmaf(a.w,x.w, acca))));
        accb = fmaf(a.x,y.x, fmaf(a.y,y.y, fmaf(a.z,y.z, fmaf(a.w,y.w, accb))));
      }
      gstore(c, ja, r0 + r, acca);
      gstore(c, jb, r0 + r, accb);
    }
  } else {
    for (int e = threadIdx.x; e < (c.J << c.LR); e += 256) {
      int r = e & (R - 1); int jj = j0 + (e >> c.LR);
      if (jj < c.N) {
        const float4* wa = (const float4*)(c.W + (size_t)jj * c.wstr + c.wofs);
        const float4* ar = (const float4*)(sm + r * Kp);
        float acc = c.bias ? c.bias[jj] : 0.f;
        for (int k4 = 0; k4 < k4n; ++k4) {
          float4 a = ar[k4]; float4 x = wa[k4];
          acc = fmaf(a.x,x.x, fmaf(a.y,x.y, fmaf(a.z,x.z, fmaf(a.w,x.w, acc))));
        }
        gstore(c, jj, r0 + r, acc);
      }
    }
  }
}

// ---------------- striped GRU: block owns 16 gate-triples x 16 batch rows ----------------
__device__ void stripe_gru(const float* actT, int K, const float* W, int wstr, int wofs,
                           const float* giaddT, const float* bi,
                           const float* ghT, const float* bh,
                           float* hT, const float* xaddT, float* xnextT,
                           int rb, float* sm)
{
  int jg = rb & 15, rg = rb >> 4;
  int r0 = rg * 16, j0 = jg * 16;
  int Kp = K + 4;
  for (int idx = threadIdx.x; idx < (K << 4); idx += 256) {
    int k = idx >> 4, r = idx & 15;
    sm[r * Kp + k] = actT[k * 64 + r0 + r];
  }
  __syncthreads();
  int e = threadIdx.x;
  int r = e & 15, q = e >> 4;
  int j = j0 + q, b = r0 + r;
  const float4* w0 = (const float4*)(W + (size_t)j * wstr + wofs);
  const float4* w1 = (const float4*)(W + (size_t)(j + 256) * wstr + wofs);
  const float4* w2 = (const float4*)(W + (size_t)(j + 512) * wstr + wofs);
  const float4* ar = (const float4*)(sm + r * Kp);
  float a0 = 0.f, a1 = 0.f, a2 = 0.f;
  for (int k4 = 0; k4 < (K >> 2); ++k4) {
    float4 a = ar[k4];
    float4 x = w0[k4], y = w1[k4], z4 = w2[k4];
    a0 = fmaf(a.x,x.x, fmaf(a.y,x.y, fmaf(a.z,x.z, fmaf(a.w,x.w, a0))));
    a1 = fmaf(a.x,y.x, fmaf(a.y,y.y, fmaf(a.z,y.z, fmaf(a.w,y.w, a1))));
    a2 = fmaf(a.x,z4.x, fmaf(a.y,z4.y, fmaf(a.z,z4.z, fmaf(a.w,z4.w, a2))));
  }
  if (giaddT) {
    a0 += giaddT[j * 64 + b];
    a1 += giaddT[(j + 256) * 64 + b];
    a2 += giaddT[(j + 512) * 64 + b];
  }
  float gr = a0 + bi[j], gz = a1 + bi[j + 256], gn = a2 + bi[j + 512];
  float hr = ghT[j * 64 + b] + bh[j];
  float hz = ghT[(j + 256) * 64 + b] + bh[j + 256];
  float hn = ghT[(j + 512) * 64 + b] + bh[j + 512];
  float rr = 1.f / (1.f + expf(-(gr + hr)));
  float zz = 1.f / (1.f + expf(-(gz + hz)));
  float nn = tanhf(gn + rr * hn);
  float h = hT[j * 64 + b];
  float hnew = (1.f - zz) * nn + zz * h;
  hT[j * 64 + b] = hnew;
  if (xnextT) xnextT[j * 64 + b] = xaddT[j * 64 + b] + hnew;
}

// ---------------- static conv + prior (reads prev alpha) ----------------
__device__ void conv_fp(const KArgs& A, int item, float* sm) {
  int b = item >> 2, s0 = (item & 3) * 128;
  float* sal = sm;
  float* sdF = sm + 160;
  for (int i = threadIdx.x; i < 148; i += 256) {
    int sg = s0 - 10 + i;
    sal[i] = (sg >= 0 && sg < 512) ? A.ws[OFF_ALPHA + b * 512 + sg] : 0.f;
  }
  for (int i = threadIdx.x; i < 168; i += 256) sdF[i] = A.dFw[i];
  __syncthreads();
  for (int q = threadIdx.x; q < 1024; q += 256) {
    int sl = q >> 3, ch = q & 7;
    float fa = 0.f;
#pragma unroll
    for (int k = 0; k < 21; ++k) fa = fmaf(sdF[ch * 21 + k], sal[sl + k], fa);
    A.ws[OFF_F8 + ((size_t)b * 512 + s0 + sl) * 8 + ch] = fa;
  }
  if (threadIdx.x < 128) {
    int sl = threadIdx.x;
    float p = 0.f;
#pragma unroll
    for (int k = 0; k < 11; ++k) p = fmaf(A.pr.v[k], sal[sl + k], p);
    A.ws[OFF_LOGP + b * 512 + s0 + sl] = logf(fmaxf(p, 1e-6f));
  }
  __syncthreads();
}

// ---------------- dynamic conv + energy MLP ----------------
__device__ void dyn_e(const KArgs& A, float* sm) {
  int b = blockIdx.x >> 2, s0 = (blockIdx.x & 3) * 128;
  float* sal = sm;            // 148 (pad 152)
  float* sG  = sm + 152;      // 168
  float* sfp = sm + 320;      // 1152
  float* sgp = sfp + 1152;    // 1152
  float* sdU = sgp + 1152;    // 1024
  float* sdT = sdU + 1024;    // 1024
  float* sdtb = sdT + 1024;   // 128
  float* sdv = sdtb + 128;    // 128
  float* slp = sdv + 128;     // 128
  float* ses = slp + 128;     // 256
  int tid = threadIdx.x;
  for (int i = tid; i < 148; i += 256) {
    int sg = s0 - 10 + i;
    sal[i] = (sg >= 0 && sg < 512) ? A.ws[OFF_ALPHA + b * 512 + sg] : 0.f;
  }
  for (int i = tid; i < 168; i += 256) sG[i] = A.ws[OFF_GT + i * 64 + b];
  for (int i = tid; i < 1024; i += 256) {
    sdU[i] = A.dUw[i]; sdT[i] = A.dTw[i];
    int sl = i >> 3, ch = i & 7;
    sfp[sl * 9 + ch] = A.ws[OFF_F8 + ((size_t)b * 512 + s0 + sl) * 8 + ch];
  }
  if (tid < 128) {
    sdtb[tid] = A.dTb[tid]; sdv[tid] = A.dvw[tid];
    slp[tid] = A.ws[OFF_LOGP + b * 512 + s0 + tid];
  }
  __syncthreads();
  for (int q = tid; q < 1024; q += 256) {
    int sl = q >> 3, ch = q & 7;
    float ga = 0.f;
#pragma unroll
    for (int k = 0; k < 21; ++k) ga = fmaf(sG[ch * 21 + k], sal[sl + k], ga);
    sgp[sl * 9 + ch] = ga;
  }
  __syncthreads();
  int sl = tid & 127, half = tid >> 7;
  float f0[8], g0[8];
#pragma unroll
  for (int r2 = 0; r2 < 8; ++r2) { f0[r2] = sfp[sl * 9 + r2]; g0[r2] = sgp[sl * 9 + r2]; }
  float acc = 0.f;
  for (int cc = half * 64; cc < half * 64 + 64; ++cc) {
    float a = sdtb[cc];
#pragma unroll
    for (int r2 = 0; r2 < 8; ++r2) a = fmaf(sdU[cc * 8 + r2], f0[r2], fmaf(sdT[cc * 8 + r2], g0[r2], a));
    acc = fmaf(sdv[cc], tanhf(a), acc);
  }
  ses[half * 128 + sl] = acc;
  __syncthreads();
  if (tid < 128)
    A.ws[OFF_E + b * 512 + s0 + tid] = ses[tid] + ses[128 + tid] + slp[tid];
}

// ---------------- softmax + sparse context ----------------
__device__ void softmax_ctx(const KArgs& A, float* sm) {
  int b = blockIdx.x, tid = threadIdx.x;
  float* red = sm;                 // 4 (pad 8)
  int* wc = (int*)(sm + 8);        // 8
  float* lv = sm + 16;             // 512
  short* li = (short*)(sm + 528);  // 512 shorts
  float e0 = A.ws[OFF_E + b * 512 + tid];
  float e1 = A.ws[OFF_E + b * 512 + 256 + tid];
  float m = fmaxf(e0, e1);
  for (int o = 32; o; o >>= 1) m = fmaxf(m, __shfl_xor(m, o));
  int lane = tid & 63, wv = tid >> 6;
  if (lane == 0) red[wv] = m;
  __syncthreads();
  m = fmaxf(fmaxf(red[0], red[1]), fmaxf(red[2], red[3]));
  float p0 = expf(e0 - m), p1 = expf(e1 - m);
  float s = p0 + p1;
  for (int o = 32; o; o >>= 1) s += __shfl_xor(s, o);
  __syncthreads();
  if (lane == 0) red[wv] = s;
  __syncthreads();
  float inv = 1.f / (red[0] + red[1] + red[2] + red[3]);
  float a0 = p0 * inv, a1 = p1 * inv;
  A.ws[OFF_ALPHA + b * 512 + tid] = a0;
  A.ws[OFF_ALPHA + b * 512 + 256 + tid] = a1;
  unsigned long long m0 = __ballot(a0 > EPS_A);
  unsigned long long m1 = __ballot(a1 > EPS_A);
  if (lane == 0) { wc[wv] = (int)__popcll(m0); wc[4 + wv] = (int)__popcll(m1); }
  __syncthreads();
  int base0 = 0;
  for (int w = 0; w < wv; ++w) base0 += wc[w];
  int totalA = wc[0] + wc[1] + wc[2] + wc[3];
  int base1 = totalA;
  for (int w = 0; w < wv; ++w) base1 += wc[4 + w];
  int n = totalA + wc[4] + wc[5] + wc[6] + wc[7];
  unsigned long long below = (1ull << lane) - 1ull;
  if (a0 > EPS_A) { int p = base0 + (int)__popcll(m0 & below); li[p] = (short)tid; lv[p] = a0; }
  if (a1 > EPS_A) { int p = base1 + (int)__popcll(m1 & below); li[p] = (short)(256 + tid); lv[p] = a1; }
  __syncthreads();
  const float* encb = A.enc + (size_t)b * 512 * 768;
  for (int d = tid; d < 768; d += 256) {
    float acc = 0.f;
    for (int i = 0; i < n; ++i) acc = fmaf(lv[i], encb[(size_t)li[i] * 768 + d], acc);
    A.ws[OFF_CTX + d * 64 + b] = acc;
  }
}

// ---------------- the persistent decoder ----------------
__global__ __launch_bounds__(256, 1) void k_decode(KArgs A) {
  __shared__ __align__(16) float sm[16448];
  __shared__ unsigned sgen;
  if (threadIdx.x == 0) sgen = 0;
  __syncthreads();
  float* ws = A.ws;
  int blk = blockIdx.x;

  for (int t = 0; t <= TDEC; ++t) {
    // ---- S0: proj(t-1) || gi_ctx || gh_att || gh1 || gh2 ----
    if (blk < 64) {
      if (t > 0) {
        GemmCfg c{ws + OFF_X3, nullptr, 256, 256, A.prw, 256, 0, A.prb, ws + OFF_FRAME,
                  400, 25, 16, 4, 0, 1, A.dout, t - 1};
        gemm_run(c, blk, sm);
      }
    } else if (t < TDEC) {
      if (blk < 160) {
        GemmCfg c{ws + OFF_CTX, nullptr, 768, 768, A.awi, 896, 0, nullptr, ws + OFF_GICTX,
                  768, 32, 24, 4, 0, 0, nullptr, 0};
        gemm_run(c, blk - 64, sm);
      } else if (blk < 192) {
        GemmCfg c{ws + OFF_HATT, nullptr, 256, 256, A.awh, 256, 0, nullptr, ws + OFF_GHATT,
                  768, 48, 16, 5, 0, 0, nullptr, 0};
        gemm_run(c, blk - 160, sm);
      } else if (blk < 224) {
        GemmCfg c{ws + OFF_H1, nullptr, 256, 256, A.g1wh, 256, 0, nullptr, ws + OFF_GH1,
                  768, 48, 16, 5, 0, 0, nullptr, 0};
        gemm_run(c, blk - 192, sm);
      } else {
        GemmCfg c{ws + OFF_H2, nullptr, 256, 256, A.g2wh, 256, 0, nullptr, ws + OFF_GH2,
                  768, 48, 16, 5, 0, 0, nullptr, 0};
        gemm_run(c, blk - 224, sm);
      }
    }
    if (t == TDEC) break;
    gridbar(ws, &sgen);

    // ---- S1: prenet L1 || static conv + prior ----
    if (blk < 64) {
      GemmCfg c{ws + OFF_FRAME, nullptr, 400, 400, A.p1w, 400, 0, A.p1b, ws + OFF_H1S,
                256, 16, 16, 4, 1, 0, nullptr, 0};
      gemm_run(c, blk, sm);
    } else {
      int rel = blk - 64;
      for (int item = rel; item < 256; item += 192) conv_fp(A, item, sm);
    }
    gridbar(ws, &sgen);

    // ---- S2: prenet L2 ----
    if (blk < 64) {
      GemmCfg c{ws + OFF_H1S, nullptr, 256, 256, A.p2w, 256, 0, A.p2b, ws + OFF_PRE,
                128, 8, 16, 4, 1, 0, nullptr, 0};
      gemm_run(c, blk, sm);
    }
    gridbar(ws, &sgen);

    // ---- S3: gi_pre + attention GRU gates (striped) ----
    if (blk < 64)
      stripe_gru(ws + OFF_PRE, 128, A.awi, 896, 768, ws + OFF_GICTX, A.abi,
                 ws + OFF_GHATT, A.abh, ws + OFF_HATT, nullptr, nullptr, blk, sm);
    gridbar(ws, &sgen);

    // ---- S4: t1 = tanh(dW @ h_att + dWb) ----
    if (blk < 64) {
      GemmCfg c{ws + OFF_HATT, nullptr, 256, 256, A.dWw, 256, 0, A.dWb, ws + OFF_T1,
                128, 8, 16, 4, 2, 0, nullptr, 0};
      gemm_run(c, blk, sm);
    }
    gridbar(ws, &sgen);

    // ---- S5: G = dV @ t1 ----
    if (blk < 64) {
      GemmCfg c{ws + OFF_T1, nullptr, 128, 128, A.dVw, 128, 0, nullptr, ws + OFF_GT,
                168, 11, 16, 4, 0, 0, nullptr, 0};
      gemm_run(c, blk, sm);
    }
    gridbar(ws, &sgen);

    // ---- S6: dynamic conv + energy MLP ----
    dyn_e(A, sm);
    gridbar(ws, &sgen);

    // ---- S7: softmax + sparse context ----
    if (blk < 64) softmax_ctx(A, sm);
    gridbar(ws, &sgen);

    // ---- S8: x = [ctx; h_att] @ lw + lb ----
    if (blk < 64) {
      GemmCfg c{ws + OFF_CTX, ws + OFF_HATT, 768, 1024, A.lw, 1024, 0, A.lb, ws + OFF_X,
                256, 16, 16, 4, 0, 0, nullptr, 0};
      gemm_run(c, blk, sm);
    }
    gridbar(ws, &sgen);

    // ---- S9: GRU1 (striped) -> h1, x2 ----
    if (blk < 64)
      stripe_gru(ws + OFF_X, 256, A.g1wi, 256, 0, nullptr, A.g1bi,
                 ws + OFF_GH1, A.g1bh, ws + OFF_H1, ws + OFF_X, ws + OFF_X2, blk, sm);
    gridbar(ws, &sgen);

    // ---- S10: GRU2 (striped) -> h2, x3 ----
    if (blk < 64)
      stripe_gru(ws + OFF_X2, 256, A.g2wi, 256, 0, nullptr, A.g2bi,
                 ws + OFF_GH2, A.g2bh, ws + OFF_H2, ws + OFF_X2, ws + OFF_X3, blk, sm);
    gridbar(ws, &sgen);
  }
}

// ---------------- host ----------------
extern "C" void kernel_launch(void* const* d_in, const int* in_sizes, int n_in,
                              void* d_out, int out_size, void* d_ws, size_t ws_size,
                              hipStream_t stream) {
  (void)in_sizes; (void)n_in; (void)out_size; (void)ws_size;
  KArgs A;
  A.enc  = (const float*)d_in[0];
  A.p1w  = (const float*)d_in[1];  A.p1b  = (const float*)d_in[2];
  A.p2w  = (const float*)d_in[3];  A.p2b  = (const float*)d_in[4];
  A.awi  = (const float*)d_in[5];  A.abi  = (const float*)d_in[6];
  A.awh  = (const float*)d_in[7];  A.abh  = (const float*)d_in[8];
  A.dWw  = (const float*)d_in[9];  A.dWb  = (const float*)d_in[10];
  A.dVw  = (const float*)d_in[11]; A.dFw  = (const float*)d_in[12];
  A.dUw  = (const float*)d_in[13]; A.dTw  = (const float*)d_in[14];
  A.dTb  = (const float*)d_in[15]; A.dvw  = (const float*)d_in[16];
  A.lw   = (const float*)d_in[17]; A.lb   = (const float*)d_in[18];
  A.g1wi = (const float*)d_in[19]; A.g1bi = (const float*)d_in[20];
  A.g1wh = (const float*)d_in[21]; A.g1bh = (const float*)d_in[22];
  A.g2wi = (const float*)d_in[23]; A.g2bi = (const float*)d_in[24];
  A.g2wh = (const float*)d_in[25]; A.g2bh = (const float*)d_in[26];
  A.prw  = (const float*)d_in[27]; A.prb  = (const float*)d_in[28];
  A.ws   = (float*)d_ws;
  A.dout = (float*)d_out;

  // beta-binomial prior pmf (n=10, a=0.1, b=0.9), flipped
  {
    double aP = 0.1, bP = 0.9;
    double logB0 = lgamma(aP) + lgamma(bP) - lgamma(aP + bP);
    double pm[11];
    for (int k = 0; k <= 10; ++k) {
      double logC = lgamma(11.0) - lgamma(k + 1.0) - lgamma(11.0 - k);
      double logBt = lgamma(k + aP) + lgamma(10.0 - k + bP) - lgamma(10.0 + aP + bP);
      pm[k] = exp(logC + logBt - logB0);
    }
    for (int k = 0; k < 11; ++k) A.pr.v[k] = (float)pm[10 - k];
  }

  k_init<<<256, 256, 0, stream>>>((float*)d_ws);
  k_decode<<<NB, 256, 0, stream>>>(A);
}